// Round 17
// baseline (182.441 us; speedup 1.0000x reference)
//
#include <hip/hip_runtime.h>
#include <stdint.h>

typedef int v4i __attribute__((ext_vector_type(4)));

#define EPS_F32 1.1920928955078125e-07f   // np.finfo(float32).eps = 2^-23

// ---------------------------------------------------------------------------
// rss kernel: rss[k] = 1/ss[k] (exact IEEE div, once).
// ---------------------------------------------------------------------------
__global__ __launch_bounds__(256) void rss_kernel(
    const float* __restrict__ ss, float* __restrict__ rss, int DIN)
{
    const int i = blockIdx.x * 256 + threadIdx.x;
    if (i < DIN) rss[i] = 1.0f / ss[i];
}

// ---------------------------------------------------------------------------
// Fused quant kernel (r16, at memory floor): X blocks multiply by rss,
// W blocks multiply by ss; one reciprocal per thread for the scale.
// ---------------------------------------------------------------------------
__global__ __launch_bounds__(256) void quant_kernel(
    const float* __restrict__ X, const float* __restrict__ W,
    const float* __restrict__ ss, const float* __restrict__ rss,
    int8_t* __restrict__ Xq, float* __restrict__ xs,
    int8_t* __restrict__ Wq, float* __restrict__ ws,
    int DIN, int M)
{
    const int bid = blockIdx.x;
    const int tid = threadIdx.x;
    const bool isX = bid < M;
    const float* row  = isX ? X + (size_t)bid * DIN
                            : W + (size_t)(bid - M) * DIN;
    const float* svec = isX ? rss : ss;

    float4 v[4];
    float amax = 0.f;
#pragma unroll
    for (int c = 0; c < 4; ++c) {
        const int k = c * 1024 + tid * 4;
        float4 xv = *(const float4*)(row + k);
        float4 sv = *(const float4*)(svec + k);
        float4 q;
        q.x = xv.x * sv.x; q.y = xv.y * sv.y;
        q.z = xv.z * sv.z; q.w = xv.w * sv.w;
        v[c] = q;
        amax = fmaxf(amax, fmaxf(fmaxf(fabsf(q.x), fabsf(q.y)),
                                 fmaxf(fabsf(q.z), fabsf(q.w))));
    }
    __shared__ float red[4];
    for (int off = 32; off; off >>= 1) amax = fmaxf(amax, __shfl_xor(amax, off));
    const int lane = tid & 63, w = tid >> 6;
    if (lane == 0) red[w] = amax;
    __syncthreads();
    amax = fmaxf(fmaxf(red[0], red[1]), fmaxf(red[2], red[3]));

    float scale, lo;
    if (isX) { scale = fmaxf(amax, 1e-5f) / 127.0f;      lo = -127.f; }
    else     { scale = fmaxf(amax / 127.5f, EPS_F32);    lo = -128.f; }
    if (tid == 0) { if (isX) xs[bid] = scale; else ws[bid - M] = scale; }
    const float rscale = 1.0f / scale;

    int* qout = isX ? (int*)(Xq + (size_t)bid * DIN)
                    : (int*)(Wq + (size_t)(bid - M) * DIN);
#pragma unroll
    for (int c = 0; c < 4; ++c) {
        float4 q = v[c];
        int b0 = (int)fminf(fmaxf(rintf(q.x * rscale), lo), 127.f);
        int b1 = (int)fminf(fmaxf(rintf(q.y * rscale), lo), 127.f);
        int b2 = (int)fminf(fmaxf(rintf(q.z * rscale), lo), 127.f);
        int b3 = (int)fminf(fmaxf(rintf(q.w * rscale), lo), 127.f);
        qout[c * 256 + tid] = (b0 & 255) | ((b1 & 255) << 8) |
                              ((b2 & 255) << 16) | ((b3 & 255) << 24);
    }
}

// ---------------------------------------------------------------------------
// Persistent 2-tile int8 NT GEMM, 256x256 tiles, BKB=128, 8 waves (2x4),
// 128 KiB dbuf LDS, mfma_i32_16x16x64_i8, grid 256.
//
// ROUND 17: COUNTED-vmcnt 4-phase (T4, m218: counted vs drain0 = +38-73%).
// Stages split lo4 (A rows 0-127 + B rows 0-127) / hi4 (rows 128-255),
// matching the aLo/aHi row-half fragment split.  Per kt:
//   P0: issue lo4(t+1) then hi4(t+1) -> buf^1 ; MFMA LL (aLo x bLo)
//   P1: vmcnt(8)  [retires hi4(t), the oldest 4; t+1's 8 stay in flight]
//       s_barrier ; read aHi,bHi (buf t) ; MFMA LH (aLo x bHi)
//   P2: MFMA HL (aHi x bLo)
//   P3: MFMA HH (aHi x bHi)   <- consumes bHi BEFORE the barrier (WAR-safe:
//       when any wave passes this barrier, every wave's cur-buf reads are
//       retired, so P0(t+1)'s DMA into the other buffer... and P0(t+2)'s
//       into THIS buffer, 2 barriers later, cannot race)
//       vmcnt(4)  [retires lo4(t+1)] ; s_barrier ; read aLo,bLo (buf t+1)
// Steady state never drains to 0 -> waves slip past each other; loads span
// barriers (the m201/AITER pattern).
// Ledger: prologue {stage lo4,hi4(kt0); vmcnt(4); bar; read lo} enters
// steady state with hi4(kt0) in flight.  Last kt: pf=false -> P1 uses
// vmcnt(0) (queue = hi4 only; counted 8 would be a no-op race — the r5
// lesson), P3's vmcnt(4) is a harmless no-op on an empty queue.
// Seg boundary: rollover staging keeps pf=true at seg0's tail; epilogue
// stores are OLDER than kt1's stages, so seg1-P1's vmcnt(8) retires
// hi4+stores together.  acc re-zeroed between segs.
// ---------------------------------------------------------------------------
#define BM 256
#define BN 256
#define BKB 128

#define MFMA __builtin_amdgcn_mfma_i32_16x16x64_i8

__global__ __launch_bounds__(512, 2) void gemm_i8_kernel(
    const int8_t* __restrict__ Xq, const int8_t* __restrict__ Wq,
    const float* __restrict__ xs, const float* __restrict__ ws,
    const float* __restrict__ bias, float* __restrict__ Y,
    int M, int N, int K)
{
    __shared__ __align__(16) int8_t smem[131072];

    const int tid  = threadIdx.x;
    const int lane = tid & 63;
    const int w    = tid >> 6;
    const int wrow = w >> 2, wcol = w & 3;

    const int bid    = blockIdx.x;
    const int xcd    = bid & 7, idx = bid >> 3;        // idx in [0,32)
    const int bmBase = (xcd >> 1) * 8 + (idx >> 3);    // seg0 bm; seg1 = +4
    const int bn     = (xcd & 1) * 8 + (idx & 7);

    const int srcSwz = ((lane & 7) ^ (lane >> 3)) << 4;  // staging source swizzle
    const int chnk0  = ((lane >> 4) ^ (lane & 7)) << 4;  // frag read, k-slice 0
    const int chnk1  = chnk0 ^ 64;                       // k-slice 1
    const int aRB = ((wrow << 6) + (lane & 15)) << 7;    // A frag row-byte base
    const int bRB = ((wcol << 5) + (lane & 15)) << 7;    // B frag row-byte base

    auto STAGE = [&](const int8_t* gtile, int region, int rowStart) {
        const int8_t* src = gtile +
            (size_t)(rowStart + (w << 3) + (lane >> 3)) * K + srcSwz;
        __builtin_amdgcn_global_load_lds(
            (const __attribute__((address_space(1))) void*)src,
            (__attribute__((address_space(3))) void*)(smem + region + ((rowStart + (w << 3)) << 7)),
            16, 0, 0);
    };

    v4i acc[8][4] = {};
    v4i aLo[4][2], aHi[4][2], bLo[2][2], bHi[2][2];

    const int KT = K / BKB;   // 32
    const int8_t* bT0 = Wq + (size_t)bn * BN * K;   // same B panel both segs
    const int rowb = (lane >> 4) << 2;
    const int col  = lane & 15;

    // prologue: stage kt0 (lo4 then hi4) into buf0; counted wait; read lo
    {
        const int8_t* aT0 = Xq + (size_t)bmBase * BM * K;
        STAGE(aT0, 0,     0);   STAGE(aT0, 0,     64);    // lo4: A rows 0-127
        STAGE(bT0, 32768, 0);   STAGE(bT0, 32768, 64);    //      B rows 0-127
        STAGE(aT0, 0,     128); STAGE(aT0, 0,     192);   // hi4: A rows 128-255
        STAGE(bT0, 32768, 128); STAGE(bT0, 32768, 192);   //      B rows 128-255
        asm volatile("s_waitcnt vmcnt(4)" ::: "memory");   // lo4 landed
        __builtin_amdgcn_s_barrier();
#pragma unroll
        for (int i = 0; i < 4; ++i) {
            aLo[i][0] = *(const v4i*)(smem + aRB + i * 2048 + chnk0);
            aLo[i][1] = *(const v4i*)(smem + aRB + i * 2048 + chnk1);
        }
#pragma unroll
        for (int j = 0; j < 2; ++j) {
            bLo[j][0] = *(const v4i*)(smem + 32768 + bRB + j * 2048 + chnk0);
            bLo[j][1] = *(const v4i*)(smem + 32768 + bRB + j * 2048 + chnk1);
        }
    }

    for (int seg = 0; seg < 2; ++seg) {
        const int bm = bmBase + seg * 4;
        const int8_t* aT0 = Xq + (size_t)bm * BM * K;

        for (int kt = 0; kt < KT; ++kt) {
            const int Ab  = (kt & 1) * 65536;
            const int Bb  = Ab + 32768;
            const int nAb = ((kt & 1) ^ 1) * 65536;
            const int nBb = nAb + 32768;
            const bool more = (kt + 1 < KT);
            const bool pf   = more || (seg == 0);
            const int8_t* aTn = more ? aT0 + (size_t)(kt + 1) * BKB
                                     : Xq + (size_t)(bmBase + 4) * BM * K;
            const int8_t* bTn = more ? bT0 + (size_t)(kt + 1) * BKB : bT0;

            // ---- P0: stage lo4(t+1) then hi4(t+1); MFMA LL
            if (pf) { STAGE(aTn, nAb, 0);   STAGE(aTn, nAb, 64);
                      STAGE(bTn, nBb, 0);   STAGE(bTn, nBb, 64);
                      STAGE(aTn, nAb, 128); STAGE(aTn, nAb, 192);
                      STAGE(bTn, nBb, 128); STAGE(bTn, nBb, 192); }
            __builtin_amdgcn_s_setprio(1);
#pragma unroll
            for (int i = 0; i < 4; ++i)
#pragma unroll
                for (int j = 0; j < 2; ++j) {
                    acc[i][j] = MFMA(aLo[i][0], bLo[j][0], acc[i][j], 0, 0, 0);
                    acc[i][j] = MFMA(aLo[i][1], bLo[j][1], acc[i][j], 0, 0, 0);
                }
            __builtin_amdgcn_s_setprio(0);

            // ---- P1: counted wait for hi4(t); read aHi/bHi; MFMA LH
            if (pf) asm volatile("s_waitcnt vmcnt(8)" ::: "memory"); // hi4(t) landed
            else    asm volatile("s_waitcnt vmcnt(0)" ::: "memory"); // last kt: drain
            __builtin_amdgcn_s_barrier();
#pragma unroll
            for (int i = 0; i < 4; ++i) {
                aHi[i][0] = *(const v4i*)(smem + Ab + aRB + 16384 + i * 2048 + chnk0);
                aHi[i][1] = *(const v4i*)(smem + Ab + aRB + 16384 + i * 2048 + chnk1);
            }
#pragma unroll
            for (int j = 0; j < 2; ++j) {
                bHi[j][0] = *(const v4i*)(smem + Bb + bRB + 16384 + j * 2048 + chnk0);
                bHi[j][1] = *(const v4i*)(smem + Bb + bRB + 16384 + j * 2048 + chnk1);
            }
            __builtin_amdgcn_s_setprio(1);
#pragma unroll
            for (int i = 0; i < 4; ++i)
#pragma unroll
                for (int j = 0; j < 2; ++j) {
                    acc[i][2 + j] = MFMA(aLo[i][0], bHi[j][0], acc[i][2 + j], 0, 0, 0);
                    acc[i][2 + j] = MFMA(aLo[i][1], bHi[j][1], acc[i][2 + j], 0, 0, 0);
                }
            __builtin_amdgcn_s_setprio(0);

            // ---- P2: MFMA HL
            __builtin_amdgcn_s_setprio(1);
#pragma unroll
            for (int i = 0; i < 4; ++i)
#pragma unroll
                for (int j = 0; j < 2; ++j) {
                    acc[4 + i][j] = MFMA(aHi[i][0], bLo[j][0], acc[4 + i][j], 0, 0, 0);
                    acc[4 + i][j] = MFMA(aHi[i][1], bLo[j][1], acc[4 + i][j], 0, 0, 0);
                }
            __builtin_amdgcn_s_setprio(0);

            // ---- P3: MFMA HH (consumes bHi pre-barrier); counted wait lo4(t+1);
            //          read aLo/bLo(t+1)
            __builtin_amdgcn_s_setprio(1);
#pragma unroll
            for (int i = 0; i < 4; ++i)
#pragma unroll
                for (int j = 0; j < 2; ++j) {
                    acc[4 + i][2 + j] = MFMA(aHi[i][0], bHi[j][0], acc[4 + i][2 + j], 0, 0, 0);
                    acc[4 + i][2 + j] = MFMA(aHi[i][1], bHi[j][1], acc[4 + i][2 + j], 0, 0, 0);
                }
            __builtin_amdgcn_s_setprio(0);
            asm volatile("s_waitcnt vmcnt(4)" ::: "memory");  // lo4(t+1) landed (no-op on last kt)
            __builtin_amdgcn_s_barrier();
            if (pf) {
#pragma unroll
                for (int i = 0; i < 4; ++i) {
                    aLo[i][0] = *(const v4i*)(smem + nAb + aRB + i * 2048 + chnk0);
                    aLo[i][1] = *(const v4i*)(smem + nAb + aRB + i * 2048 + chnk1);
                }
#pragma unroll
                for (int j = 0; j < 2; ++j) {
                    bLo[j][0] = *(const v4i*)(smem + nBb + bRB + j * 2048 + chnk0);
                    bLo[j][1] = *(const v4i*)(smem + nBb + bRB + j * 2048 + chnk1);
                }
            }
        }

        // ----- epilogue: dequant + bias (layout col=lane&15, row=(lane>>4)*4+reg)
        {
            float wsv[4], bv[4];
#pragma unroll
            for (int j = 0; j < 4; ++j) {
                const int n = bn * BN + ((j >> 1) << 7) + (wcol << 5) + ((j & 1) << 4) + col;
                wsv[j] = ws[n];
                bv[j]  = bias[n];
            }
#pragma unroll
            for (int i = 0; i < 8; ++i) {
                const int mbase = bm * BM + ((i >> 2) << 7) + (wrow << 6) + ((i & 3) << 4) + rowb;
#pragma unroll
                for (int r = 0; r < 4; ++r) {
                    const int m = mbase + r;
                    const float xsm = xs[m];
                    float* yrow = Y + (size_t)m * N;
#pragma unroll
                    for (int j = 0; j < 4; ++j) {
                        const int n = bn * BN + ((j >> 1) << 7) + (wcol << 5) + ((j & 1) << 4) + col;
                        yrow[n] = (float)acc[i][j][r] * xsm * wsv[j] + bv[j];
                    }
                }
            }
        }

        if (seg == 0) {
#pragma unroll
            for (int i = 0; i < 8; ++i)
#pragma unroll
                for (int j = 0; j < 4; ++j)
                    acc[i][j] = (v4i){0, 0, 0, 0};
        }
    }
}

// ---------------------------------------------------------------------------
extern "C" void kernel_launch(void* const* d_in, const int* in_sizes, int n_in,
                              void* d_out, int out_size, void* d_ws, size_t ws_size,
                              hipStream_t stream) {
    const float* X    = (const float*)d_in[0];
    const float* W    = (const float*)d_in[1];
    const float* bias = (const float*)d_in[2];
    const float* ss   = (const float*)d_in[3];

    const int DIN  = in_sizes[3];              // 4096
    const int DOUT = in_sizes[2];              // 4096
    const int M    = in_sizes[0] / DIN;        // 8192

    int8_t* Xq  = (int8_t*)d_ws;
    int8_t* Wq  = Xq + (size_t)M * DIN;
    float*  xs  = (float*)(Wq + (size_t)DOUT * DIN);
    float*  ws  = xs + M;
    float*  rss = ws + DOUT;
    float*  Y   = (float*)d_out;

    rss_kernel<<<(DIN + 255) / 256, 256, 0, stream>>>(ss, rss, DIN);
    quant_kernel<<<M + DOUT, 256, 0, stream>>>(X, W, ss, rss, Xq, xs, Wq, ws, DIN, M);
    gemm_i8_kernel<<<(M / BM) * (DOUT / BN) / 2, 512, 0, stream>>>(Xq, Wq, xs, ws, bias, Y, M, DOUT, DIN);
}

// Round 18
// 173.009 us; speedup vs baseline: 1.0545x; 1.0545x over previous
//
#include <hip/hip_runtime.h>
#include <stdint.h>

typedef int v4i __attribute__((ext_vector_type(4)));

#define EPS_F32 1.1920928955078125e-07f   // np.finfo(float32).eps = 2^-23

// ---------------------------------------------------------------------------
// rss kernel: rss[k] = 1/ss[k] (exact IEEE div, once) so the X-quant path
// becomes a pure multiply.  ss > 0 always (ratio of positive absmaxes).
// ---------------------------------------------------------------------------
__global__ __launch_bounds__(256) void rss_kernel(
    const float* __restrict__ ss, float* __restrict__ rss, int DIN)
{
    const int i = blockIdx.x * 256 + threadIdx.x;
    if (i < DIN) rss[i] = 1.0f / ss[i];
}

// ---------------------------------------------------------------------------
// Fused quant kernel: blocks [0,M) per-token X quant (multiply by rss),
// blocks [M,M+DOUT) per-out-channel W quant (multiply by ss).  Both paths
// are the same branchless q = v*s; one reciprocal per thread for the scale.
// At the ~38us memory floor (240 MB @ ~6.3 TB/s).
// ---------------------------------------------------------------------------
__global__ __launch_bounds__(256) void quant_kernel(
    const float* __restrict__ X, const float* __restrict__ W,
    const float* __restrict__ ss, const float* __restrict__ rss,
    int8_t* __restrict__ Xq, float* __restrict__ xs,
    int8_t* __restrict__ Wq, float* __restrict__ ws,
    int DIN, int M)
{
    const int bid = blockIdx.x;
    const int tid = threadIdx.x;
    const bool isX = bid < M;
    const float* row  = isX ? X + (size_t)bid * DIN
                            : W + (size_t)(bid - M) * DIN;
    const float* svec = isX ? rss : ss;

    float4 v[4];
    float amax = 0.f;
#pragma unroll
    for (int c = 0; c < 4; ++c) {
        const int k = c * 1024 + tid * 4;
        float4 xv = *(const float4*)(row + k);
        float4 sv = *(const float4*)(svec + k);
        float4 q;
        q.x = xv.x * sv.x; q.y = xv.y * sv.y;
        q.z = xv.z * sv.z; q.w = xv.w * sv.w;
        v[c] = q;
        amax = fmaxf(amax, fmaxf(fmaxf(fabsf(q.x), fabsf(q.y)),
                                 fmaxf(fabsf(q.z), fabsf(q.w))));
    }
    __shared__ float red[4];
    for (int off = 32; off; off >>= 1) amax = fmaxf(amax, __shfl_xor(amax, off));
    const int lane = tid & 63, w = tid >> 6;
    if (lane == 0) red[w] = amax;
    __syncthreads();
    amax = fmaxf(fmaxf(red[0], red[1]), fmaxf(red[2], red[3]));

    float scale, lo;
    if (isX) { scale = fmaxf(amax, 1e-5f) / 127.0f;      lo = -127.f; }
    else     { scale = fmaxf(amax / 127.5f, EPS_F32);    lo = -128.f; }
    if (tid == 0) { if (isX) xs[bid] = scale; else ws[bid - M] = scale; }
    const float rscale = 1.0f / scale;   // one exact div; then 16 muls

    int* qout = isX ? (int*)(Xq + (size_t)bid * DIN)
                    : (int*)(Wq + (size_t)(bid - M) * DIN);
#pragma unroll
    for (int c = 0; c < 4; ++c) {
        float4 q = v[c];
        int b0 = (int)fminf(fmaxf(rintf(q.x * rscale), lo), 127.f);
        int b1 = (int)fminf(fmaxf(rintf(q.y * rscale), lo), 127.f);
        int b2 = (int)fminf(fmaxf(rintf(q.z * rscale), lo), 127.f);
        int b3 = (int)fminf(fmaxf(rintf(q.w * rscale), lo), 127.f);
        qout[c * 256 + tid] = (b0 & 255) | ((b1 & 255) << 8) |
                              ((b2 & 255) << 16) | ((b3 & 255) << 24);
    }
}

// ---------------------------------------------------------------------------
// Persistent 2-tile int8 NT GEMM — round-10 structure (best measured,
// replay-validated).  256x256 tiles, BKB=128, 8 waves (2x4), 128 KiB dbuf
// LDS, mfma_i32_16x16x64_i8, grid 256 (1 block/CU), K-half sub-steps:
//   S0: 8 stages(next tile) + read fHI(cur) + MFMA(fLO)  -> vmcnt(0)+barrier
//   S1: read fLO(next buf)                  + MFMA(fHI)
// Session conclusion: 10 schedule/geometry variants (r7-r17) all land
// 132-159us; LDS-read (~2300cy/kt) and MFMA (~2600cy/kt) do not overlap
// under any intra-block reordering — this is the structure's floor.
// ---------------------------------------------------------------------------
#define BM 256
#define BN 256
#define BKB 128

#define MFMA __builtin_amdgcn_mfma_i32_16x16x64_i8

__global__ __launch_bounds__(512, 2) void gemm_i8_kernel(
    const int8_t* __restrict__ Xq, const int8_t* __restrict__ Wq,
    const float* __restrict__ xs, const float* __restrict__ ws,
    const float* __restrict__ bias, float* __restrict__ Y,
    int M, int N, int K)
{
    __shared__ __align__(16) int8_t smem[131072];

    const int tid  = threadIdx.x;
    const int lane = tid & 63;
    const int w    = tid >> 6;
    const int wrow = w >> 2, wcol = w & 3;

    const int bid    = blockIdx.x;
    const int xcd    = bid & 7, idx = bid >> 3;        // idx in [0,32)
    const int bmBase = (xcd >> 1) * 8 + (idx >> 3);    // seg0 bm; seg1 = +4
    const int bn     = (xcd & 1) * 8 + (idx & 7);

    const int srcSwz = ((lane & 7) ^ (lane >> 3)) << 4;  // staging source swizzle
    const int chnk0  = ((lane >> 4) ^ (lane & 7)) << 4;  // frag read, k-slice 0
    const int chnk1  = chnk0 ^ 64;                       // k-slice 1
    const int aRB = ((wrow << 6) + (lane & 15)) << 7;    // A frag row-byte base
    const int bRB = ((wcol << 5) + (lane & 15)) << 7;    // B frag row-byte base

    auto STAGE = [&](const int8_t* gtile, int region, int rowStart) {
        const int8_t* src = gtile +
            (size_t)(rowStart + (w << 3) + (lane >> 3)) * K + srcSwz;
        __builtin_amdgcn_global_load_lds(
            (const __attribute__((address_space(1))) void*)src,
            (__attribute__((address_space(3))) void*)(smem + region + ((rowStart + (w << 3)) << 7)),
            16, 0, 0);
    };

    v4i acc[8][4] = {};
    v4i fLA[8], fHA[8], fLB[4], fHB[4];   // K-half fragment sets (static names)

    const int KT = K / BKB;   // 32
    const int8_t* bT0 = Wq + (size_t)bn * BN * K;   // same B panel both segs
    const int rowb = (lane >> 4) << 2;
    const int col  = lane & 15;

    // prologue: stage tile (seg0,kt0) into buf0; read fLO from buf0
    {
        const int8_t* aT0 = Xq + (size_t)bmBase * BM * K;
        STAGE(aT0, 0,     0);   STAGE(aT0, 0,     64);
        STAGE(aT0, 0,     128); STAGE(aT0, 0,     192);
        STAGE(bT0, 32768, 0);   STAGE(bT0, 32768, 64);
        STAGE(bT0, 32768, 128); STAGE(bT0, 32768, 192);
        asm volatile("s_waitcnt vmcnt(0)" ::: "memory");
        __builtin_amdgcn_s_barrier();
#pragma unroll
        for (int i = 0; i < 4; ++i) {
            fLA[i]     = *(const v4i*)(smem + aRB + i * 2048 + chnk0);
            fLA[4 + i] = *(const v4i*)(smem + aRB + 16384 + i * 2048 + chnk0);
        }
#pragma unroll
        for (int j = 0; j < 2; ++j) {
            fLB[j]     = *(const v4i*)(smem + 32768 + bRB + j * 2048 + chnk0);
            fLB[2 + j] = *(const v4i*)(smem + 32768 + bRB + 16384 + j * 2048 + chnk0);
        }
    }

    for (int seg = 0; seg < 2; ++seg) {
        const int bm = bmBase + seg * 4;
        const int8_t* aT0 = Xq + (size_t)bm * BM * K;

        for (int kt = 0; kt < KT; ++kt) {
            const int Ab  = (kt & 1) * 65536;
            const int Bb  = Ab + 32768;
            const int nAb = ((kt & 1) ^ 1) * 65536;
            const int nBb = nAb + 32768;
            const bool more = (kt + 1 < KT);
            const bool pf   = more || (seg == 0);
            const int8_t* aTn = more ? aT0 + (size_t)(kt + 1) * BKB
                                     : Xq + (size_t)(bmBase + 4) * BM * K;
            const int8_t* bTn = more ? bT0 + (size_t)(kt + 1) * BKB : bT0;

            // ---- S0: 8 stages; read fHI(cur); MFMA on fLO (K 0..64)
            if (pf) { STAGE(aTn, nAb, 0);   STAGE(aTn, nAb, 64);
                      STAGE(aTn, nAb, 128); STAGE(aTn, nAb, 192);
                      STAGE(bTn, nBb, 0);   STAGE(bTn, nBb, 64);
                      STAGE(bTn, nBb, 128); STAGE(bTn, nBb, 192); }
#pragma unroll
            for (int i = 0; i < 4; ++i) {
                fHA[i]     = *(const v4i*)(smem + Ab + aRB + i * 2048 + chnk1);
                fHA[4 + i] = *(const v4i*)(smem + Ab + aRB + 16384 + i * 2048 + chnk1);
            }
#pragma unroll
            for (int j = 0; j < 2; ++j) {
                fHB[j]     = *(const v4i*)(smem + Bb + bRB + j * 2048 + chnk1);
                fHB[2 + j] = *(const v4i*)(smem + Bb + bRB + 16384 + j * 2048 + chnk1);
            }
            __builtin_amdgcn_s_setprio(1);
#pragma unroll
            for (int i = 0; i < 8; ++i)
#pragma unroll
                for (int j = 0; j < 4; ++j)
                    acc[i][j] = MFMA(fLA[i], fLB[j], acc[i][j], 0, 0, 0);
            __builtin_amdgcn_s_setprio(0);
            asm volatile("s_waitcnt vmcnt(0)" ::: "memory");  // all 8 stages landed
            __builtin_amdgcn_s_barrier();

            // ---- S1: read fLO(next buf); MFMA on fHI (K 64..128)
            if (pf) {
#pragma unroll
                for (int i = 0; i < 4; ++i) {
                    fLA[i]     = *(const v4i*)(smem + nAb + aRB + i * 2048 + chnk0);
                    fLA[4 + i] = *(const v4i*)(smem + nAb + aRB + 16384 + i * 2048 + chnk0);
                }
#pragma unroll
                for (int j = 0; j < 2; ++j) {
                    fLB[j]     = *(const v4i*)(smem + nBb + bRB + j * 2048 + chnk0);
                    fLB[2 + j] = *(const v4i*)(smem + nBb + bRB + 16384 + j * 2048 + chnk0);
                }
            }
            __builtin_amdgcn_s_setprio(1);
#pragma unroll
            for (int i = 0; i < 8; ++i)
#pragma unroll
                for (int j = 0; j < 4; ++j)
                    acc[i][j] = MFMA(fHA[i], fHB[j], acc[i][j], 0, 0, 0);
            __builtin_amdgcn_s_setprio(0);
        }

        // ----- epilogue: dequant + bias (layout col=lane&15, row=(lane>>4)*4+reg)
        {
            float wsv[4], bv[4];
#pragma unroll
            for (int j = 0; j < 4; ++j) {
                const int n = bn * BN + ((j >> 1) << 7) + (wcol << 5) + ((j & 1) << 4) + col;
                wsv[j] = ws[n];
                bv[j]  = bias[n];
            }
#pragma unroll
            for (int i = 0; i < 8; ++i) {
                const int mbase = bm * BM + ((i >> 2) << 7) + (wrow << 6) + ((i & 3) << 4) + rowb;
#pragma unroll
                for (int r = 0; r < 4; ++r) {
                    const int m = mbase + r;
                    const float xsm = xs[m];
                    float* yrow = Y + (size_t)m * N;
#pragma unroll
                    for (int j = 0; j < 4; ++j) {
                        const int n = bn * BN + ((j >> 1) << 7) + (wcol << 5) + ((j & 1) << 4) + col;
                        yrow[n] = (float)acc[i][j][r] * xsm * wsv[j] + bv[j];
                    }
                }
            }
        }

        if (seg == 0) {
#pragma unroll
            for (int i = 0; i < 8; ++i)
#pragma unroll
                for (int j = 0; j < 4; ++j)
                    acc[i][j] = (v4i){0, 0, 0, 0};
        }
    }
}

// ---------------------------------------------------------------------------
extern "C" void kernel_launch(void* const* d_in, const int* in_sizes, int n_in,
                              void* d_out, int out_size, void* d_ws, size_t ws_size,
                              hipStream_t stream) {
    const float* X    = (const float*)d_in[0];
    const float* W    = (const float*)d_in[1];
    const float* bias = (const float*)d_in[2];
    const float* ss   = (const float*)d_in[3];

    const int DIN  = in_sizes[3];              // 4096
    const int DOUT = in_sizes[2];              // 4096
    const int M    = in_sizes[0] / DIN;        // 8192

    int8_t* Xq  = (int8_t*)d_ws;
    int8_t* Wq  = Xq + (size_t)M * DIN;
    float*  xs  = (float*)(Wq + (size_t)DOUT * DIN);
    float*  ws  = xs + M;
    float*  rss = ws + DOUT;
    float*  Y   = (float*)d_out;

    rss_kernel<<<(DIN + 255) / 256, 256, 0, stream>>>(ss, rss, DIN);
    quant_kernel<<<M + DOUT, 256, 0, stream>>>(X, W, ss, rss, Xq, xs, Wq, ws, DIN, M);
    gemm_i8_kernel<<<(M / BM) * (DOUT / BN) / 2, 512, 0, stream>>>(Xq, Wq, xs, ws, bias, Y, M, DOUT, DIN);
}